// Round 9
// baseline (401.538 us; speedup 1.0000x reference)
//
#include <hip/hip_runtime.h>
#include <hip/hip_bf16.h>
#include <hip/hip_fp16.h>
#include <math.h>

#define HID 128
#define INDIM 256
// Bucketed CSR build: bucket = dst>>7 (128 dsts/bucket), NB = ceil(N/128) <= 512.
// Requires N <= 65536 so (dst,src) pack into one uint32. N = 50000 here.
#define CAP 6144          // slots per bucket region (avg ~4096, binomial max ~4400)
#define NBLK1 512         // pass-1 blocks

typedef _Float16 h2v __attribute__((ext_vector_type(2)));

#ifndef __has_builtin
#define __has_builtin(x) 0
#endif
#if __has_builtin(__builtin_amdgcn_fdot2)
#define FDOT2(a, b, c) __builtin_amdgcn_fdot2((a), (b), (c), false)
#else
__device__ __forceinline__ float FDOT2(h2v a, h2v b, float c) {
    return fmaf((float)a[0], (float)b[0], fmaf((float)a[1], (float)b[1], c));
}
#endif

// ---------------- edge dtype detection ----------------
__global__ void detect_i64_kernel(const int* __restrict__ idx32, int* __restrict__ flag) {
    int l = threadIdx.x;             // 0..63
    int v = idx32[2 * l + 1];
    unsigned long long ball = __ballot(v != 0);
    if (l == 0) flag[0] = (ball == 0ULL) ? 1 : 0;
}

__device__ __forceinline__ int load_src(const int* idx, int is64, int E, int e) {
    return is64 ? idx[2 * e] : idx[e];
}
__device__ __forceinline__ int load_dst(const int* idx, int is64, int E, int e) {
    return is64 ? idx[2 * (E + e)] : idx[E + e];
}

// ---------------- pass 1: LDS-binned bucket scatter ----------------
__global__ __launch_bounds__(256) void bucket_scatter_kernel(const int* __restrict__ idx32,
                                                             const int* __restrict__ flag,
                                                             int* __restrict__ bcursor,
                                                             unsigned int* __restrict__ recs,
                                                             int E, int NB) {
    __shared__ int hist[512];
    __shared__ int cur[512];
    int t = threadIdx.x;
    int CH = (E + NBLK1 - 1) / NBLK1;
    int e0 = blockIdx.x * CH;
    int e1 = min(e0 + CH, E);
    for (int i = t; i < NB; i += 256) hist[i] = 0;
    __syncthreads();
    int is64 = flag[0];
    for (int e = e0 + t; e < e1; e += 256) {
        int d = load_dst(idx32, is64, E, e);
        atomicAdd(&hist[d >> 7], 1);
    }
    __syncthreads();
    for (int i = t; i < NB; i += 256)
        cur[i] = atomicAdd(&bcursor[i], hist[i]);   // reserve range in bucket i
    __syncthreads();
    for (int e = e0 + t; e < e1; e += 256) {
        int s = load_src(idx32, is64, E, e);
        int d = load_dst(idx32, is64, E, e);
        int b = d >> 7;
        int r = atomicAdd(&cur[b], 1);              // LDS rank
        recs[(size_t)b * CAP + r] = ((unsigned)d << 16) | (unsigned)s;
    }
}

// ---------------- pass 2: exclusive scan of NB bucket totals (NB <= 512) ----------------
__global__ void bucket_scan_kernel(const int* __restrict__ bcursor,
                                   int* __restrict__ bbase, int NB) {
    int l = threadIdx.x;   // 64 threads
    int i0 = l * 8;
    int v[8];
    #pragma unroll
    for (int k = 0; k < 8; k++) v[k] = (i0 + k < NB) ? bcursor[i0 + k] : 0;
    int s = 0;
    #pragma unroll
    for (int k = 0; k < 8; k++) s += v[k];
    int x = s;
    #pragma unroll
    for (int off = 1; off < 64; off <<= 1) {
        int y = __shfl_up(x, off);
        if (l >= off) x += y;
    }
    int run = x - s;
    #pragma unroll
    for (int k = 0; k < 8; k++) {
        if (i0 + k < NB) bbase[i0 + k] = run;
        run += v[k];
    }
}

// ---------------- pass 3: finalize CSR (one block per bucket) ----------------
__global__ __launch_bounds__(256) void csr_finalize_kernel(const unsigned int* __restrict__ recs,
                                                           const int* __restrict__ bcursor,
                                                           const int* __restrict__ bbase,
                                                           int* __restrict__ rowstart,
                                                           int* __restrict__ csr_src,
                                                           int N, int E) {
    __shared__ int h[128];
    __shared__ int ex[128];
    __shared__ int cu[128];
    int b = blockIdx.x;
    int t = threadIdx.x;
    int cnt = bcursor[b];
    int base = bbase[b];
    if (t < 128) h[t] = 0;
    __syncthreads();
    const unsigned int* r0 = recs + (size_t)b * CAP;
    for (int i = t; i < cnt; i += 256) {
        unsigned int rec = r0[i];
        atomicAdd(&h[(rec >> 16) & 127], 1);
    }
    __syncthreads();
    if (t < 64) {
        int a0 = h[2 * t], a1 = h[2 * t + 1];
        int s = a0 + a1;
        int x = s;
        #pragma unroll
        for (int off = 1; off < 64; off <<= 1) {
            int y = __shfl_up(x, off);
            if (t >= off) x += y;
        }
        ex[2 * t] = x - s;
        ex[2 * t + 1] = x - s + a0;
    }
    __syncthreads();
    int d0 = b * 128;
    if (t < 128) {
        if (d0 + t < N) rowstart[d0 + t] = base + ex[t];
        cu[t] = ex[t];
    }
    if (b == 0 && t == 0) rowstart[N] = E;
    __syncthreads();
    for (int i = t; i < cnt; i += 256) {
        unsigned int rec = r0[i];
        int dl = (rec >> 16) & 127;
        int r = atomicAdd(&cu[dl], 1);              // LDS rank within dst
        csr_src[base + r] = (int)(rec & 0xffffu);
    }
}

// ---------------- encoder: h16 = relu(x @ W + b) via packed-fp16 dot2, fp32 accum ----
__global__ __launch_bounds__(256) void encoder_kernel(const float* __restrict__ x,
                                                      const float* __restrict__ W,
                                                      const float* __restrict__ b,
                                                      const float* __restrict__ attw,
                                                      const float* __restrict__ attb,
                                                      __half* __restrict__ h16,
                                                      float* __restrict__ ai,
                                                      float* __restrict__ aj, int N) {
    __shared__ h2v xsp[16][68];     // 4352 B
    __shared__ h2v wspT[16][132];   // 8448 B
    int t = threadIdx.x;
    int n0 = blockIdx.x * 64;
    int tc = t & 15, tr = t >> 4;
    int c0 = tc * 8, r0 = tr * 4;
    float acc[4][8];
    #pragma unroll
    for (int i = 0; i < 4; i++)
        #pragma unroll
        for (int j = 0; j < 8; j++) acc[i][j] = 0.f;

    int lr = t >> 2, lc4 = (t & 3) * 8;
    int wcg = t & 15, wk2 = t >> 4;

    for (int k0 = 0; k0 < INDIM; k0 += 32) {
        int gr = n0 + lr; if (gr >= N) gr = N - 1;
        const float4* xg = (const float4*)(x + (size_t)gr * INDIM + k0 + lc4);
        float4 a0 = xg[0], a1 = xg[1];
        int kb = lc4 >> 1;
        { h2v p; p[0] = (_Float16)a0.x; p[1] = (_Float16)a0.y; xsp[kb + 0][lr] = p; }
        { h2v p; p[0] = (_Float16)a0.z; p[1] = (_Float16)a0.w; xsp[kb + 1][lr] = p; }
        { h2v p; p[0] = (_Float16)a1.x; p[1] = (_Float16)a1.y; xsp[kb + 2][lr] = p; }
        { h2v p; p[0] = (_Float16)a1.z; p[1] = (_Float16)a1.w; xsp[kb + 3][lr] = p; }
        {
            const float4* w0 = (const float4*)(W + (size_t)(k0 + 2 * wk2) * HID + wcg * 8);
            const float4* w1 = (const float4*)(W + (size_t)(k0 + 2 * wk2 + 1) * HID + wcg * 8);
            float4 r0a = w0[0], r0b = w0[1];
            float4 r1a = w1[0], r1b = w1[1];
            union { float4 f; h2v h[4]; } ua, ub;
            ua.h[0][0] = (_Float16)r0a.x; ua.h[0][1] = (_Float16)r1a.x;
            ua.h[1][0] = (_Float16)r0a.y; ua.h[1][1] = (_Float16)r1a.y;
            ua.h[2][0] = (_Float16)r0a.z; ua.h[2][1] = (_Float16)r1a.z;
            ua.h[3][0] = (_Float16)r0a.w; ua.h[3][1] = (_Float16)r1a.w;
            ub.h[0][0] = (_Float16)r0b.x; ub.h[0][1] = (_Float16)r1b.x;
            ub.h[1][0] = (_Float16)r0b.y; ub.h[1][1] = (_Float16)r1b.y;
            ub.h[2][0] = (_Float16)r0b.z; ub.h[2][1] = (_Float16)r1b.z;
            ub.h[3][0] = (_Float16)r0b.w; ub.h[3][1] = (_Float16)r1b.w;
            *(float4*)&wspT[wcg][wk2 * 8]     = ua.f;
            *(float4*)&wspT[wcg][wk2 * 8 + 4] = ub.f;
        }
        __syncthreads();
        #pragma unroll
        for (int kk2 = 0; kk2 < 16; ++kk2) {
            union { float4 f; h2v h[4]; } ux, uw0, uw1;
            ux.f  = *(const float4*)&xsp[kk2][r0];
            uw0.f = *(const float4*)&wspT[tc][kk2 * 8];
            uw1.f = *(const float4*)&wspT[tc][kk2 * 8 + 4];
            #pragma unroll
            for (int i = 0; i < 4; i++) {
                #pragma unroll
                for (int j = 0; j < 4; j++) {
                    acc[i][j]     = FDOT2(ux.h[i], uw0.h[j], acc[i][j]);
                    acc[i][j + 4] = FDOT2(ux.h[i], uw1.h[j], acc[i][j + 4]);
                }
            }
        }
        __syncthreads();
    }
    float wiv[8], wjv[8];
    #pragma unroll
    for (int j = 0; j < 8; j++) { wiv[j] = attw[c0 + j]; wjv[j] = attw[HID + c0 + j]; }
    #pragma unroll
    for (int i = 0; i < 4; i++) {
        int gr = n0 + r0 + i;
        float ov[8];
        #pragma unroll
        for (int j = 0; j < 8; j++) {
            float o = acc[i][j] + b[c0 + j];
            ov[j] = o > 0.f ? o : 0.f;
        }
        if (gr < N) {
            union { float4 f; __half2 h[4]; } u;
            #pragma unroll
            for (int j = 0; j < 8; j += 2)
                u.h[j >> 1] = __float22half2_rn(make_float2(ov[j], ov[j + 1]));
            *(float4*)(h16 + (size_t)gr * HID + c0) = u.f;
        }
        float pi = 0.f, pj = 0.f;
        #pragma unroll
        for (int j = 0; j < 8; j++) { pi = fmaf(ov[j], wiv[j], pi); pj = fmaf(ov[j], wjv[j], pj); }
        #pragma unroll
        for (int off = 1; off < 16; off <<= 1) {
            pi += __shfl_xor(pi, off);
            pj += __shfl_xor(pj, off);
        }
        if (tc == 0 && gr < N) { ai[gr] = pi + attb[0]; aj[gr] = pj; }
    }
}

// ---------------- care aggregation, XCD feature-sliced ----------------
// Block b: chunk c = b&3 (32 features = ONE 64B line per h row), dst group m = b>>2,
// wave w -> dst n = m*4+w. With blockIdx%8 -> XCD round-robin, chunk c runs on
// XCDs {c, c+4}: per-XCD gather working set = N*64B = 3.2MB < 4MB L2 -> L2-resident.
// Wave = 16 edge-slots x 4 feature-lanes (float4 each). Chunked 64-edge prefetch
// computes sigmoid once per edge, vectorized across lanes.
// MODE 0: hh_out chunk + attproj2 partials (aip/ajp[c*N+n])
// MODE 1: classifier partials outp[(c*N+n)*2]
template <int MODE>
__global__ __launch_bounds__(256) void care2_kernel(const __half* __restrict__ hh,
                                                    const float* __restrict__ ai,
                                                    const float* __restrict__ aj,
                                                    const int* __restrict__ rowstart,
                                                    const int* __restrict__ csr_src,
                                                    __half* __restrict__ hh_out,
                                                    float* __restrict__ aip,
                                                    float* __restrict__ ajp,
                                                    float* __restrict__ outp, int N,
                                                    const float* __restrict__ attw2,
                                                    const float* __restrict__ clsw) {
    int b = blockIdx.x;
    int c = b & 3;                 // feature chunk (one 64B line of each h row)
    int m = b >> 2;                // dst group
    int t = threadIdx.x;
    int lane = t & 63, w = t >> 6;
    int n = m * 4 + w;
    if (n >= N) return;
    int beg = rowstart[n], end = rowstart[n + 1];
    int deg = end - beg;
    float ain = ai[n];
    int es = lane >> 2;            // edge slot 0..15
    int fl = lane & 3;             // feature lane: float4 #fl of the chunk

    float acc[8];
    #pragma unroll
    for (int k = 0; k < 8; k++) acc[k] = 0.f;

    const float4* hp = (const float4*)hh;   // 16 float4 per row
    int fofs = c * 4 + fl;
    for (int c0 = beg; c0 < end; c0 += 64) {
        int mm = end - c0; if (mm > 64) mm = 64;
        int li = lane < mm ? lane : mm - 1;
        int sl = csr_src[c0 + li];                 // 64 indices, coalesced
        float ajl = aj[sl];                        // 64 gathers in flight
        float al = 1.0f / (1.0f + __expf(-(ain + ajl)));
        if (lane >= mm) al = 0.f;
        int nit = (mm + 15) >> 4;
        #pragma unroll 4
        for (int it = 0; it < nit; ++it) {
            int idx = it * 16 + es;                // <= 63 always
            float a = __shfl(al, idx);
            int s = __shfl(sl, idx);
            float4 hv = hp[(size_t)s * 16 + fofs];
            union { float4 f; __half2 h[4]; } u; u.f = hv;
            #pragma unroll
            for (int k = 0; k < 4; k++) {
                float2 fv = __half22float2(u.h[k]);
                acc[2 * k + 0] = fmaf(a, fv.x, acc[2 * k + 0]);
                acc[2 * k + 1] = fmaf(a, fv.y, acc[2 * k + 1]);
            }
        }
    }
    // combine the 16 edge slots (butterfly over lane bits 2..5)
    #pragma unroll
    for (int k = 0; k < 8; k++) {
        acc[k] += __shfl_xor(acc[k], 4);
        acc[k] += __shfl_xor(acc[k], 8);
        acc[k] += __shfl_xor(acc[k], 16);
        acc[k] += __shfl_xor(acc[k], 32);
    }
    float scale = 1.0f / fmaxf((float)deg, 1.0f);

    if (MODE == 0) {
        float mv[8];
        #pragma unroll
        for (int k = 0; k < 8; k++) {
            float o = acc[k] * scale;
            mv[k] = o > 0.f ? o : 0.f;
        }
        if (es == 0) {
            union { float4 f; __half2 h[4]; } u;
            #pragma unroll
            for (int k = 0; k < 4; k++)
                u.h[k] = __float22half2_rn(make_float2(mv[2 * k], mv[2 * k + 1]));
            ((float4*)hh_out)[(size_t)n * 16 + fofs] = u.f;
        }
        // attproj2 chunk-partial
        float pi = 0.f, pj = 0.f;
        #pragma unroll
        for (int k = 0; k < 8; k++) {
            int f = c * 32 + fl * 8 + k;
            pi = fmaf(mv[k], attw2[f], pi);
            pj = fmaf(mv[k], attw2[HID + f], pj);
        }
        pi += __shfl_xor(pi, 1); pi += __shfl_xor(pi, 2);
        pj += __shfl_xor(pj, 1); pj += __shfl_xor(pj, 2);
        if (lane == 0) { aip[(size_t)c * N + n] = pi; ajp[(size_t)c * N + n] = pj; }
    } else {
        float p0 = 0.f, p1 = 0.f;
        #pragma unroll
        for (int k = 0; k < 8; k++) {
            float mvv = acc[k] * scale;
            int f = c * 32 + fl * 8 + k;
            p0 = fmaf(mvv, clsw[f * 2 + 0], p0);
            p1 = fmaf(mvv, clsw[f * 2 + 1], p1);
        }
        p0 += __shfl_xor(p0, 1); p0 += __shfl_xor(p0, 2);
        p1 += __shfl_xor(p1, 1); p1 += __shfl_xor(p1, 2);
        if (lane == 0) {
            outp[((size_t)c * N + n) * 2 + 0] = p0;
            outp[((size_t)c * N + n) * 2 + 1] = p1;
        }
    }
}

// ---------------- combine chunk partials ----------------
__global__ __launch_bounds__(256) void combine_att_kernel(const float* __restrict__ aip,
                                                          const float* __restrict__ ajp,
                                                          const float* __restrict__ attb2,
                                                          float* __restrict__ ai2,
                                                          float* __restrict__ aj2, int N) {
    int i = blockIdx.x * 256 + threadIdx.x;
    if (i >= N) return;
    ai2[i] = aip[i] + aip[(size_t)N + i] + aip[2 * (size_t)N + i] + aip[3 * (size_t)N + i] + attb2[0];
    aj2[i] = ajp[i] + ajp[(size_t)N + i] + ajp[2 * (size_t)N + i] + ajp[3 * (size_t)N + i];
}

__global__ __launch_bounds__(256) void combine_out_kernel(const float* __restrict__ outp,
                                                          const float* __restrict__ clsb,
                                                          float* __restrict__ out, int N) {
    int i = blockIdx.x * 256 + threadIdx.x;
    if (i >= N) return;
    float o0 = 0.f, o1 = 0.f;
    #pragma unroll
    for (int cc = 0; cc < 4; cc++) {
        o0 += outp[((size_t)cc * N + i) * 2 + 0];
        o1 += outp[((size_t)cc * N + i) * 2 + 1];
    }
    out[(size_t)i * 2 + 0] = o0 + clsb[0];
    out[(size_t)i * 2 + 1] = o1 + clsb[1];
}

extern "C" void kernel_launch(void* const* d_in, const int* in_sizes, int n_in,
                              void* d_out, int out_size, void* d_ws, size_t ws_size,
                              hipStream_t stream) {
    const float* x      = (const float*)d_in[0];
    const int*   idx32  = (const int*)d_in[1];
    const float* enc_w  = (const float*)d_in[2];
    const float* enc_b  = (const float*)d_in[3];
    const float* att1_w = (const float*)d_in[4];
    const float* att1_b = (const float*)d_in[5];
    const float* att2_w = (const float*)d_in[6];
    const float* att2_b = (const float*)d_in[7];
    const float* cls_w  = (const float*)d_in[8];
    const float* cls_b  = (const float*)d_in[9];
    float* out = (float*)d_out;

    int N = in_sizes[0] / INDIM;      // 50000
    int E = in_sizes[1] / 2;          // 1.6M
    int NB = (N + 127) >> 7;          // buckets (391, <= 512)
    int G4 = ((N + 3) / 4) * 4;       // care2 grid: 4 chunks x ceil(N/4) groups

    // workspace carve-up (~47 MB)
    char* p = (char*)d_ws;
    __half* h16a = (__half*)p; p += (size_t)N * HID * 2;
    __half* h16b = (__half*)p; p += (size_t)N * HID * 2;
    int* csr_src  = (int*)p; p += (size_t)E * 4;
    unsigned int* recs = (unsigned int*)p; p += (size_t)NB * CAP * 4;
    float* ai   = (float*)p; p += (size_t)N * 4;
    float* aj   = (float*)p; p += (size_t)N * 4;
    float* ai2  = (float*)p; p += (size_t)N * 4;
    float* aj2  = (float*)p; p += (size_t)N * 4;
    float* aip  = (float*)p; p += (size_t)4 * N * 4;
    float* ajp  = (float*)p; p += (size_t)4 * N * 4;
    float* outp = (float*)p; p += (size_t)4 * N * 2 * 4;
    int* rowstart = (int*)p; p += (size_t)(N + 1) * 4;
    int* bcursor  = (int*)p; p += (size_t)NB * 4;
    int* bbase    = (int*)p; p += (size_t)NB * 4;
    int* flag     = (int*)p; p += 64;

    hipMemsetAsync(bcursor, 0, (size_t)NB * 4, stream);
    detect_i64_kernel<<<1, 64, 0, stream>>>(idx32, flag);
    bucket_scatter_kernel<<<NBLK1, 256, 0, stream>>>(idx32, flag, bcursor, recs, E, NB);
    bucket_scan_kernel<<<1, 64, 0, stream>>>(bcursor, bbase, NB);
    csr_finalize_kernel<<<NB, 256, 0, stream>>>(recs, bcursor, bbase, rowstart,
                                                csr_src, N, E);

    encoder_kernel<<<(N + 63) / 64, 256, 0, stream>>>(x, enc_w, enc_b, att1_w, att1_b,
                                                      h16a, ai, aj, N);

    care2_kernel<0><<<G4, 256, 0, stream>>>(h16a, ai, aj, rowstart, csr_src,
                                            h16b, aip, ajp, nullptr, N, att2_w, nullptr);
    combine_att_kernel<<<(N + 255) / 256, 256, 0, stream>>>(aip, ajp, att2_b, ai2, aj2, N);
    care2_kernel<1><<<G4, 256, 0, stream>>>(h16b, ai2, aj2, rowstart, csr_src,
                                            nullptr, nullptr, nullptr, outp, N,
                                            nullptr, cls_w);
    combine_out_kernel<<<(N + 255) / 256, 256, 0, stream>>>(outp, cls_b, out, N);
}

// Round 10
// 266.531 us; speedup vs baseline: 1.5065x; 1.5065x over previous
//
#include <hip/hip_runtime.h>
#include <hip/hip_bf16.h>
#include <hip/hip_fp16.h>
#include <math.h>

#define HID 128
#define INDIM 256
// Bucketed CSR build: bucket = dst>>7 (128 dsts/bucket), NB = ceil(N/128) <= 512.
// Requires N <= 65536 so (dst,src) pack into one uint32. N = 50000 here.
#define CAP 6144          // slots per bucket region (avg ~4096, binomial max ~4400)
#define NBLK1 512         // scatter blocks inside the fused kernel

typedef _Float16 h2v __attribute__((ext_vector_type(2)));

#ifndef __has_builtin
#define __has_builtin(x) 0
#endif
#if __has_builtin(__builtin_amdgcn_fdot2)
#define FDOT2(a, b, c) __builtin_amdgcn_fdot2((a), (b), (c), false)
#else
__device__ __forceinline__ float FDOT2(h2v a, h2v b, float c) {
    return fmaf((float)a[0], (float)b[0], fmaf((float)a[1], (float)b[1], c));
}
#endif

// ---------------- edge dtype detection ----------------
__global__ void detect_i64_kernel(const int* __restrict__ idx32, int* __restrict__ flag) {
    int l = threadIdx.x;             // 0..63
    int v = idx32[2 * l + 1];
    unsigned long long ball = __ballot(v != 0);
    if (l == 0) flag[0] = (ball == 0ULL) ? 1 : 0;
}

__device__ __forceinline__ int load_src(const int* idx, int is64, int E, int e) {
    return is64 ? idx[2 * e] : idx[e];
}
__device__ __forceinline__ int load_dst(const int* idx, int is64, int E, int e) {
    return is64 ? idx[2 * (E + e)] : idx[E + e];
}

// ---------------- FUSED: encoder (blocks 0..EBenc-1) + bucket scatter (rest) ----
// Independent stages overlap: encoder is VALU/LDS-heavy, scatter is memory-heavy.
// Shared-LDS union: encoder needs 12800B (xsp+wspT), scatter 4096B (hist+cur).
__global__ __launch_bounds__(256) void enc_scatter_kernel(
        const float* __restrict__ x, const float* __restrict__ W,
        const float* __restrict__ b, const float* __restrict__ attw,
        const float* __restrict__ attb, __half* __restrict__ h16,
        float* __restrict__ ai, float* __restrict__ aj, int N, int EBenc,
        const int* __restrict__ idx32, const int* __restrict__ flag,
        int* __restrict__ bcursor, unsigned int* __restrict__ recs, int E, int NB) {
    __shared__ __align__(16) char smem[12800];
    int t = threadIdx.x;

    if ((int)blockIdx.x >= EBenc) {
        // ================= bucket scatter body =================
        int* hist = (int*)smem;
        int* cur  = (int*)(smem + 2048);
        int sbid = blockIdx.x - EBenc;
        int CH = (E + NBLK1 - 1) / NBLK1;
        int e0 = sbid * CH;
        int e1 = min(e0 + CH, E);
        for (int i = t; i < NB; i += 256) hist[i] = 0;
        __syncthreads();
        int is64 = flag[0];
        for (int e = e0 + t; e < e1; e += 256) {
            int d = load_dst(idx32, is64, E, e);
            atomicAdd(&hist[d >> 7], 1);
        }
        __syncthreads();
        for (int i = t; i < NB; i += 256)
            cur[i] = atomicAdd(&bcursor[i], hist[i]);   // reserve range in bucket i
        __syncthreads();
        for (int e = e0 + t; e < e1; e += 256) {
            int s = load_src(idx32, is64, E, e);
            int d = load_dst(idx32, is64, E, e);
            int bb = d >> 7;
            int r = atomicAdd(&cur[bb], 1);             // LDS rank
            recs[(size_t)bb * CAP + r] = ((unsigned)d << 16) | (unsigned)s;
        }
        return;
    }

    // ================= encoder body (packed-fp16 dot2, fp32 accum) =================
    h2v (*xsp)[68]  = (h2v(*)[68])smem;                 // 4352 B
    h2v (*wspT)[132] = (h2v(*)[132])(smem + 4352);      // 8448 B
    int n0 = blockIdx.x * 64;
    int tc = t & 15, tr = t >> 4;
    int c0 = tc * 8, r0 = tr * 4;
    float acc[4][8];
    #pragma unroll
    for (int i = 0; i < 4; i++)
        #pragma unroll
        for (int j = 0; j < 8; j++) acc[i][j] = 0.f;

    int lr = t >> 2, lc4 = (t & 3) * 8;
    int wcg = t & 15, wk2 = t >> 4;

    for (int k0 = 0; k0 < INDIM; k0 += 32) {
        int gr = n0 + lr; if (gr >= N) gr = N - 1;
        const float4* xg = (const float4*)(x + (size_t)gr * INDIM + k0 + lc4);
        float4 a0 = xg[0], a1 = xg[1];
        int kb = lc4 >> 1;
        { h2v p; p[0] = (_Float16)a0.x; p[1] = (_Float16)a0.y; xsp[kb + 0][lr] = p; }
        { h2v p; p[0] = (_Float16)a0.z; p[1] = (_Float16)a0.w; xsp[kb + 1][lr] = p; }
        { h2v p; p[0] = (_Float16)a1.x; p[1] = (_Float16)a1.y; xsp[kb + 2][lr] = p; }
        { h2v p; p[0] = (_Float16)a1.z; p[1] = (_Float16)a1.w; xsp[kb + 3][lr] = p; }
        {
            const float4* w0 = (const float4*)(W + (size_t)(k0 + 2 * wk2) * HID + wcg * 8);
            const float4* w1 = (const float4*)(W + (size_t)(k0 + 2 * wk2 + 1) * HID + wcg * 8);
            float4 r0a = w0[0], r0b = w0[1];
            float4 r1a = w1[0], r1b = w1[1];
            union { float4 f; h2v h[4]; } ua, ub;
            ua.h[0][0] = (_Float16)r0a.x; ua.h[0][1] = (_Float16)r1a.x;
            ua.h[1][0] = (_Float16)r0a.y; ua.h[1][1] = (_Float16)r1a.y;
            ua.h[2][0] = (_Float16)r0a.z; ua.h[2][1] = (_Float16)r1a.z;
            ua.h[3][0] = (_Float16)r0a.w; ua.h[3][1] = (_Float16)r1a.w;
            ub.h[0][0] = (_Float16)r0b.x; ub.h[0][1] = (_Float16)r1b.x;
            ub.h[1][0] = (_Float16)r0b.y; ub.h[1][1] = (_Float16)r1b.y;
            ub.h[2][0] = (_Float16)r0b.z; ub.h[2][1] = (_Float16)r1b.z;
            ub.h[3][0] = (_Float16)r0b.w; ub.h[3][1] = (_Float16)r1b.w;
            *(float4*)&wspT[wcg][wk2 * 8]     = ua.f;
            *(float4*)&wspT[wcg][wk2 * 8 + 4] = ub.f;
        }
        __syncthreads();
        #pragma unroll
        for (int kk2 = 0; kk2 < 16; ++kk2) {
            union { float4 f; h2v h[4]; } ux, uw0, uw1;
            ux.f  = *(const float4*)&xsp[kk2][r0];
            uw0.f = *(const float4*)&wspT[tc][kk2 * 8];
            uw1.f = *(const float4*)&wspT[tc][kk2 * 8 + 4];
            #pragma unroll
            for (int i = 0; i < 4; i++) {
                #pragma unroll
                for (int j = 0; j < 4; j++) {
                    acc[i][j]     = FDOT2(ux.h[i], uw0.h[j], acc[i][j]);
                    acc[i][j + 4] = FDOT2(ux.h[i], uw1.h[j], acc[i][j + 4]);
                }
            }
        }
        __syncthreads();
    }
    // epilogue: bias + relu + fp16 store + fused attproj1
    float wiv[8], wjv[8];
    #pragma unroll
    for (int j = 0; j < 8; j++) { wiv[j] = attw[c0 + j]; wjv[j] = attw[HID + c0 + j]; }
    #pragma unroll
    for (int i = 0; i < 4; i++) {
        int gr = n0 + r0 + i;
        float ov[8];
        #pragma unroll
        for (int j = 0; j < 8; j++) {
            float o = acc[i][j] + b[c0 + j];
            ov[j] = o > 0.f ? o : 0.f;
        }
        if (gr < N) {
            union { float4 f; __half2 h[4]; } u;
            #pragma unroll
            for (int j = 0; j < 8; j += 2)
                u.h[j >> 1] = __float22half2_rn(make_float2(ov[j], ov[j + 1]));
            *(float4*)(h16 + (size_t)gr * HID + c0) = u.f;
        }
        float pi = 0.f, pj = 0.f;
        #pragma unroll
        for (int j = 0; j < 8; j++) { pi = fmaf(ov[j], wiv[j], pi); pj = fmaf(ov[j], wjv[j], pj); }
        #pragma unroll
        for (int off = 1; off < 16; off <<= 1) {
            pi += __shfl_xor(pi, off);
            pj += __shfl_xor(pj, off);
        }
        if (tc == 0 && gr < N) { ai[gr] = pi + attb[0]; aj[gr] = pj; }
    }
}

// ---------------- finalize CSR (one block per bucket; scan fused in prologue) ----
__global__ __launch_bounds__(256) void csr_finalize_kernel(const unsigned int* __restrict__ recs,
                                                           const int* __restrict__ bcursor,
                                                           int* __restrict__ rowstart,
                                                           int* __restrict__ csr_src,
                                                           int N, int E) {
    __shared__ int h[128];
    __shared__ int ex[128];
    __shared__ int cu[128];
    __shared__ int wred[4];
    int b = blockIdx.x;
    int t = threadIdx.x;
    int lane = t & 63, w = t >> 6;
    // fused exclusive scan: base = sum of bucket counts before b
    int partial = 0;
    for (int i = t; i < b; i += 256) partial += bcursor[i];
    #pragma unroll
    for (int off = 32; off >= 1; off >>= 1) partial += __shfl_xor(partial, off);
    if (lane == 0) wred[w] = partial;
    if (t < 128) h[t] = 0;
    __syncthreads();
    int base = wred[0] + wred[1] + wred[2] + wred[3];
    int cnt = bcursor[b];
    const unsigned int* r0 = recs + (size_t)b * CAP;
    for (int i = t; i < cnt; i += 256) {
        unsigned int rec = r0[i];
        atomicAdd(&h[(rec >> 16) & 127], 1);
    }
    __syncthreads();
    if (t < 64) {
        int a0 = h[2 * t], a1 = h[2 * t + 1];
        int s = a0 + a1;
        int x = s;
        #pragma unroll
        for (int off = 1; off < 64; off <<= 1) {
            int y = __shfl_up(x, off);
            if (t >= off) x += y;
        }
        ex[2 * t] = x - s;
        ex[2 * t + 1] = x - s + a0;
    }
    __syncthreads();
    int d0 = b * 128;
    if (t < 128) {
        if (d0 + t < N) rowstart[d0 + t] = base + ex[t];
        cu[t] = ex[t];
    }
    if (b == 0 && t == 0) rowstart[N] = E;
    __syncthreads();
    for (int i = t; i < cnt; i += 256) {
        unsigned int rec = r0[i];
        int dl = (rec >> 16) & 127;
        int r = atomicAdd(&cu[dl], 1);              // LDS rank within dst
        csr_src[base + r] = (int)(rec & 0xffffu);
    }
}

// ---------------- care aggregation: one wave per dst (round-8 proven version) ----
// Chunked edge prefetch; sigmoids vectorized across lanes; inner loop is
// shfl-broadcast + independent h-row loads.
// MODE 0: hh_out = (fp16) relu(sums/max(cnt,1)); attproj2 fused -> ai2/aj2
// MODE 1: out = (sums/max(cnt,1)) @ cls_w + cls_b   (N,2), classifier fused
template <int MODE>
__global__ __launch_bounds__(256) void care_kernel(const __half* __restrict__ hh,
                                                   const float* __restrict__ ai,
                                                   const float* __restrict__ aj,
                                                   const int* __restrict__ rowstart,
                                                   const int* __restrict__ csr_src,
                                                   float* __restrict__ out,
                                                   __half* __restrict__ hh_out,
                                                   float* __restrict__ ai2,
                                                   float* __restrict__ aj2, int N,
                                                   const float* __restrict__ attw2,
                                                   const float* __restrict__ attb2,
                                                   const float* __restrict__ clsw,
                                                   const float* __restrict__ clsb) {
    int t = threadIdx.x;
    int lane = t & 63, w = t >> 6;
    int n = blockIdx.x * 4 + w;
    if (n >= N) return;
    int beg = rowstart[n], end = rowstart[n + 1];
    int deg = end - beg;
    float ain = ai[n];
    int g = lane >> 4;        // edge subgroup 0..3
    int r = lane & 15;        // feature lane: features 8r..8r+7

    float acc[8];
    #pragma unroll
    for (int k = 0; k < 8; k++) acc[k] = 0.f;

    const float4* hp = (const float4*)hh;   // 16 float4 per row
    for (int c0 = beg; c0 < end; c0 += 64) {
        int m = end - c0; if (m > 64) m = 64;
        int li = lane < m ? lane : m - 1;
        int sl = csr_src[c0 + li];                 // 64 indices, one coalesced load
        float ajl = aj[sl];                        // 64 gathers in flight at once
        float al = 1.0f / (1.0f + __expf(-(ain + ajl)));
        if (lane >= m) al = 0.f;                   // padding edges contribute 0
        int nit = (m + 3) >> 2;
        #pragma unroll 4
        for (int it = 0; it < nit; ++it) {
            int idx = it * 4 + g;                  // <= 63 always
            float a = __shfl(al, idx);
            int s = __shfl(sl, idx);
            float4 hv = hp[(size_t)s * 16 + r];
            union { float4 f; __half2 h[4]; } u; u.f = hv;
            #pragma unroll
            for (int k = 0; k < 4; k++) {
                float2 fv = __half22float2(u.h[k]);
                acc[2 * k + 0] = fmaf(a, fv.x, acc[2 * k + 0]);
                acc[2 * k + 1] = fmaf(a, fv.y, acc[2 * k + 1]);
            }
        }
    }
    // combine the 4 edge-groups (butterfly -> all lanes hold the sums)
    #pragma unroll
    for (int k = 0; k < 8; k++) {
        acc[k] += __shfl_xor(acc[k], 16);
        acc[k] += __shfl_xor(acc[k], 32);
    }
    float scale = 1.0f / fmaxf((float)deg, 1.0f);

    if (MODE == 0) {
        float mv[8];
        #pragma unroll
        for (int k = 0; k < 8; k++) {
            float o = acc[k] * scale;
            mv[k] = o > 0.f ? o : 0.f;
        }
        if (g == 0) {
            union { float4 f; __half2 h[4]; } u;
            #pragma unroll
            for (int k = 0; k < 4; k++)
                u.h[k] = __float22half2_rn(make_float2(mv[2 * k], mv[2 * k + 1]));
            ((float4*)hh_out)[(size_t)n * 16 + r] = u.f;
        }
        // fused attproj2
        float pi = 0.f, pj = 0.f;
        #pragma unroll
        for (int k = 0; k < 8; k++) {
            int f = r * 8 + k;
            pi = fmaf(mv[k], attw2[f], pi);
            pj = fmaf(mv[k], attw2[HID + f], pj);
        }
        #pragma unroll
        for (int off = 1; off < 16; off <<= 1) {
            pi += __shfl_xor(pi, off);
            pj += __shfl_xor(pj, off);
        }
        if (lane == 0) { ai2[n] = pi + attb2[0]; aj2[n] = pj; }
    } else {
        float p0 = 0.f, p1 = 0.f;
        #pragma unroll
        for (int k = 0; k < 8; k++) {
            float m = acc[k] * scale;
            int f = r * 8 + k;
            p0 = fmaf(m, clsw[f * 2 + 0], p0);
            p1 = fmaf(m, clsw[f * 2 + 1], p1);
        }
        #pragma unroll
        for (int off = 8; off >= 1; off >>= 1) {
            p0 += __shfl_xor(p0, off);
            p1 += __shfl_xor(p1, off);
        }
        if (lane == 0) {
            out[(size_t)n * 2 + 0] = p0 + clsb[0];
            out[(size_t)n * 2 + 1] = p1 + clsb[1];
        }
    }
}

extern "C" void kernel_launch(void* const* d_in, const int* in_sizes, int n_in,
                              void* d_out, int out_size, void* d_ws, size_t ws_size,
                              hipStream_t stream) {
    const float* x      = (const float*)d_in[0];
    const int*   idx32  = (const int*)d_in[1];
    const float* enc_w  = (const float*)d_in[2];
    const float* enc_b  = (const float*)d_in[3];
    const float* att1_w = (const float*)d_in[4];
    const float* att1_b = (const float*)d_in[5];
    const float* att2_w = (const float*)d_in[6];
    const float* att2_b = (const float*)d_in[7];
    const float* cls_w  = (const float*)d_in[8];
    const float* cls_b  = (const float*)d_in[9];
    float* out = (float*)d_out;

    int N = in_sizes[0] / INDIM;      // 50000
    int E = in_sizes[1] / 2;          // 1.6M
    int NB = (N + 127) >> 7;          // buckets (391, <= 512)
    int EBenc = (N + 63) / 64;        // encoder blocks (782)

    // workspace carve-up (~43 MB)
    char* p = (char*)d_ws;
    __half* h16a = (__half*)p; p += (size_t)N * HID * 2;
    __half* h16b = (__half*)p; p += (size_t)N * HID * 2;
    int* csr_src  = (int*)p; p += (size_t)E * 4;
    unsigned int* recs = (unsigned int*)p; p += (size_t)NB * CAP * 4;
    float* ai   = (float*)p; p += (size_t)N * 4;
    float* aj   = (float*)p; p += (size_t)N * 4;
    float* ai2  = (float*)p; p += (size_t)N * 4;
    float* aj2  = (float*)p; p += (size_t)N * 4;
    int* rowstart = (int*)p; p += (size_t)(N + 1) * 4;
    int* bcursor  = (int*)p; p += (size_t)NB * 4;
    int* flag     = (int*)p; p += 64;

    hipMemsetAsync(bcursor, 0, (size_t)NB * 4, stream);
    detect_i64_kernel<<<1, 64, 0, stream>>>(idx32, flag);
    enc_scatter_kernel<<<EBenc + NBLK1, 256, 0, stream>>>(x, enc_w, enc_b, att1_w, att1_b,
                                                          h16a, ai, aj, N, EBenc,
                                                          idx32, flag, bcursor, recs, E, NB);
    csr_finalize_kernel<<<NB, 256, 0, stream>>>(recs, bcursor, rowstart, csr_src, N, E);

    care_kernel<0><<<(N + 3) / 4, 256, 0, stream>>>(h16a, ai, aj, rowstart, csr_src,
                                                    nullptr, h16b, ai2, aj2, N,
                                                    att2_w, att2_b, nullptr, nullptr);
    care_kernel<1><<<(N + 3) / 4, 256, 0, stream>>>(h16b, ai2, aj2, rowstart, csr_src,
                                                    out, nullptr, nullptr, nullptr, N,
                                                    nullptr, nullptr, cls_w, cls_b);
}